// Round 14
// baseline (617.568 us; speedup 1.0000x reference)
//
#include <hip/hip_runtime.h>
#include <hip/hip_bf16.h>
#include <math.h>

#define NN 10000
#define NE 160000
#define NF 128
#define NB 20
#define CUT 5.0f
#define TPS 136   // u16 tile row stride
#define TPF 132   // fp32 tile row stride

typedef __attribute__((ext_vector_type(8))) short short8;
typedef __attribute__((ext_vector_type(4))) float floatx4;
typedef unsigned short u16;
typedef unsigned int u32;

__device__ __forceinline__ u16 f2b(float x){
  union { __hip_bfloat16 b; u16 u; } cv;
  cv.b = __float2bfloat16(x);
  return cv.u;
}
__device__ __forceinline__ float lo_bf(u32 w){ return __uint_as_float(w << 16); }
__device__ __forceinline__ float hi_bf(u32 w){ return __uint_as_float(w & 0xFFFF0000u); }
__device__ __forceinline__ u32 packbf(float lo, float hi){
  return ((u32)f2b(hi) << 16) | (u32)f2b(lo);
}
__device__ __forceinline__ float fast_silu(float v){
  return v * __builtin_amdgcn_rcpf(1.f + __expf(-v));
}
__device__ __forceinline__ float rdf(const void* p, size_t i, int isb){
  return isb ? __bfloat162float(((const __hip_bfloat16*)p)[i]) : ((const float*)p)[i];
}

// ---------------- dtype detector: 1=bf16, 0=fp32 ----------------
__global__ __launch_bounds__(256) void k_detect(const void* __restrict__ w, int nelem,
                                                int* __restrict__ flag){
  __shared__ int cnt;
  if (threadIdx.x == 0) cnt = 0;
  __syncthreads();
  const u16* hw = (const u16*)w;
  int local = 0;
  for (int k = threadIdx.x; k < nelem; k += 256){
    u16 h = hw[k];
    int e = (h >> 7) & 0xFF;
    if ((h & 0x7FFF) == 0 || (e >= 103 && e <= 130)) local++;
  }
  atomicAdd(&cnt, local);
  __syncthreads();
  if (threadIdx.x == 0) *flag = (cnt >= (nelem * 9) / 10) ? 1 : 0;
}

// ---------------- single prep kernel ----------------
struct PrepArgs {
  const void* csrc[4]; float* cdst[4]; int cn[4];
  const void* ssrc[7]; u16* sdst[7];
  const void* mesrc;   u16* medst;
};
__global__ __launch_bounds__(256) void k_prep(PrepArgs a, const int* __restrict__ flag){
  int y = blockIdx.y;
  int isb = *flag;
  if (y < 4){
    const void* s = a.csrc[y]; float* d = a.cdst[y]; int n = a.cn[y];
    for (int i = blockIdx.x*256 + threadIdx.x; i < n; i += gridDim.x*256)
      d[i] = rdf(s, i, isb);
  } else if (y < 11){
    const void* s = a.ssrc[y-4]; u16* d = a.sdst[y-4];
    int idx = blockIdx.x*256 + threadIdx.x;
    int l = idx >> 14, rem = idx & 16383;
    int j = rem & 7, lane = (rem >> 3) & 63, tn = (rem >> 9) & 7, tk = rem >> 12;
    int k = tk*32 + ((lane >> 4) & 3)*8 + j, n = tn*16 + (lane & 15);
    d[idx] = f2b(rdf(s, (size_t)l*16384 + k*NF + n, isb));
  } else {
    int idx = blockIdx.x*256 + threadIdx.x;
    if (idx >= 3*4096) return;
    int l = idx >> 12, rem = idx & 4095;
    int j = rem & 7, lane = (rem >> 3) & 63, tn = rem >> 9;
    int k = ((lane >> 4) & 3)*8 + j, n = tn*16 + (lane & 15);
    a.medst[idx] = (k < NB) ? f2b(rdf(a.mesrc, (size_t)l*NB*NF + k*NF + n, isb)) : (u16)0;
  }
}

// ---------------- counting sort: hist -> scan -> fused scatter+embed ----------------
__global__ __launch_bounds__(256) void k_hist(const int* __restrict__ ei, int* __restrict__ count){
  int e = blockIdx.x*256 + threadIdx.x;
  if (e < NE) atomicAdd(&count[ei[e]], 1);
}
__global__ __launch_bounds__(256) void k_scan(const int* __restrict__ count,
                                              int* __restrict__ rowptr, int* __restrict__ cursor){
  __shared__ int part[256];
  const int CH = (NN + 255) / 256;
  int t = threadIdx.x;
  int base = t * CH;
  int s = 0;
  for (int k = 0; k < CH; k++){ int i = base + k; if (i < NN) s += count[i]; }
  part[t] = s;
  __syncthreads();
  for (int off = 1; off < 256; off <<= 1){
    int v = (t >= off) ? part[t - off] : 0;
    __syncthreads();
    part[t] += v;
    __syncthreads();
  }
  int run = (t == 0) ? 0 : part[t - 1];
  for (int k = 0; k < CH; k++){
    int i = base + k;
    if (i < NN){ rowptr[i] = run; cursor[i] = run; run += count[i]; }
  }
  if (t == 255) rowptr[NN] = run;
}
__global__ __launch_bounds__(256) void k_scatter_embed(const int* __restrict__ ei,
                                                       int* __restrict__ cursor,
                                                       const float* __restrict__ pos,
                                                       int* __restrict__ iis, int* __restrict__ jjs,
                                                       float* __restrict__ ds, float* __restrict__ dirs){
  int e = blockIdx.x * 256 + threadIdx.x;
  if (e >= NE) return;
  int i = ei[e], j = ei[NE + e];
  float dx = pos[j*3+0] - pos[i*3+0];
  float dy = pos[j*3+1] - pos[i*3+1];
  float dz = pos[j*3+2] - pos[i*3+2];
  float d = sqrtf(dx*dx + dy*dy + dz*dz + 1e-12f);
  float inv = 1.0f / d;
  int s = atomicAdd(&cursor[i], 1);
  iis[s] = i; jjs[s] = j;
  ds[s] = d;
  dirs[s*3+0] = dx*inv; dirs[s*3+1] = dy*inv; dirs[s*3+2] = dz*inv;
}

// ---------------- layer-0 node MLP with fused atom init ----------------
__global__ __launch_bounds__(64, 4) void k_mlp0(
    const int* __restrict__ z, const float* __restrict__ emb,
    float* __restrict__ atom,
    const u16* __restrict__ w1sw, const float* __restrict__ b1,
    const u16* __restrict__ w2sw, const float* __restrict__ b2,
    u32* __restrict__ hb)
{
  __shared__ __align__(16) u16 tileT[16][TPS];
  const int lane = threadIdx.x;
  const int q = lane >> 4, ln = lane & 15;
  const int n0 = blockIdx.x * 16;
  const int zn = z[n0 + ln];

  floatx4 c1[8];
  #pragma unroll
  for (int tn = 0; tn < 8; tn++) c1[tn] = (floatx4){0,0,0,0};
  #pragma unroll
  for (int tk = 0; tk < 4; tk++){
    const float4 u0 = *(const float4*)&emb[(size_t)zn*NF + tk*32 + q*8];
    const float4 u1 = *(const float4*)&emb[(size_t)zn*NF + tk*32 + q*8 + 4];
    *(float4*)&atom[(size_t)(n0+ln)*NF + tk*32 + q*8]     = u0;
    *(float4*)&atom[(size_t)(n0+ln)*NF + tk*32 + q*8 + 4] = u1;
    short8 a;
    a[0]=(short)f2b(u0.x); a[1]=(short)f2b(u0.y); a[2]=(short)f2b(u0.z); a[3]=(short)f2b(u0.w);
    a[4]=(short)f2b(u1.x); a[5]=(short)f2b(u1.y); a[6]=(short)f2b(u1.z); a[7]=(short)f2b(u1.w);
    #pragma unroll
    for (int tn = 0; tn < 8; tn++){
      short8 b = *(const short8*)(w1sw + (size_t)((tk*8 + tn)*64 + lane)*8);
      c1[tn] = __builtin_amdgcn_mfma_f32_16x16x32_bf16(a, b, c1[tn], 0, 0, 0);
    }
  }
  #pragma unroll
  for (int tn = 0; tn < 8; tn++){
    int n = tn*16 + ln;
    float bias = b1[n];
    #pragma unroll
    for (int r = 0; r < 4; r++)
      tileT[q*4 + r][n] = f2b(fast_silu(c1[tn][r] + bias));
  }
  floatx4 c2[8];
  #pragma unroll
  for (int tn = 0; tn < 8; tn++) c2[tn] = (floatx4){0,0,0,0};
  #pragma unroll
  for (int tk = 0; tk < 4; tk++){
    short8 a = *(const short8*)&tileT[ln][tk*32 + q*8];
    #pragma unroll
    for (int tn = 0; tn < 8; tn++){
      short8 b = *(const short8*)(w2sw + (size_t)((tk*8 + tn)*64 + lane)*8);
      c2[tn] = __builtin_amdgcn_mfma_f32_16x16x32_bf16(a, b, c2[tn], 0, 0, 0);
    }
  }
  float b2n[8];
  #pragma unroll
  for (int tn = 0; tn < 8; tn++) b2n[tn] = b2[tn*16 + ln];
  #pragma unroll
  for (int tn = 0; tn < 4; tn++){
    #pragma unroll
    for (int r = 0; r < 4; r++){
      float vl = c2[tn][r]   + b2n[tn];
      float vh = c2[tn+4][r] + b2n[tn+4];
      hb[(size_t)(n0 + q*4 + r)*64 + tn*16 + ln] = packbf(vl, vh);
    }
  }
}

// ---------------- MFMA edge kernel: 2 waves/block, wave-private tiles, barrier-free ----------------
// (128,2): 256-reg budget (body needs ~110 — no spill). Doubles waves/CU past the
// single-wave-workgroup dispatch cap seen in r13 (occupancy 20% w/ 108 VGPR, 13KB LDS).
__global__ __launch_bounds__(128, 2) void k_edge_mfma(
    const int* __restrict__ iis, const int* __restrict__ jjs,
    const float* __restrict__ ds, const float* __restrict__ dirs,
    const u32* __restrict__ hb,
    const u16* __restrict__ mesw,
    const u16* __restrict__ w11sw, const u16* __restrict__ w12sw,
    const u16* __restrict__ w21sw, const u16* __restrict__ w22sw,
    float* __restrict__ atom, const u32* __restrict__ forceb, float* __restrict__ fdelta)
{
  __shared__ __align__(16) u16 tileM[2][16][TPS];
  __shared__ __align__(16) float tileF[2][16][TPF];
  __shared__ int iiS[2][16];

  const int wv = threadIdx.x >> 6;
  const int lane = threadIdx.x & 63;
  const int q = lane >> 4, ln = lane & 15;
  const int e0 = (blockIdx.x*2 + wv) * 16;   // grid = NE/32 exactly
  const int c0 = lane * 2;

  if (lane < 16) iiS[wv][lane] = iis[e0 + lane];

  int iiR[4], jjR[4];
  float dirR[4][3];
  #pragma unroll
  for (int r = 0; r < 4; r++){
    int s = e0 + q*4 + r;
    iiR[r] = iis[s]; jjR[r] = jjs[s];
    dirR[r][0] = dirs[s*3+0]; dirR[r][1] = dirs[s*3+1]; dirR[r][2] = dirs[s*3+2];
  }

  u32 hiw[4][4], hjw[4][4];
  #pragma unroll
  for (int r = 0; r < 4; r++)
    #pragma unroll
    for (int t4 = 0; t4 < 4; t4++){
      hiw[r][t4] = hb[(size_t)iiR[r]*64 + t4*16 + ln];
      hjw[r][t4] = hb[(size_t)jjR[r]*64 + t4*16 + ln];
    }

  float dA  = ds[e0 + ln];
  float fcA = (dA < CUT) ? 0.5f*(cosf((float)M_PI*dA*(1.0f/CUT)) + 1.0f) : 0.0f;
  short8 a_rbf;
  #pragma unroll
  for (int j = 0; j < 8; j++){
    int k = q*8 + j;
    float v = 0.f;
    if (k < NB){
      float t = (dA - CUT*(float)k/(float)(NB-1)) * ((float)NB/CUT);
      v = __expf(-t*t) * fcA;
    }
    a_rbf[j] = (short)f2b(v);
  }

  // me = rbf @ meW; msg -> tileF (fp32 flush) + tileM (bf16 MFMA)
  #pragma unroll
  for (int tn = 0; tn < 8; tn++){
    short8 b = *(const short8*)(mesw + (size_t)(tn*64 + lane)*8);
    floatx4 c = {0.f,0.f,0.f,0.f};
    c = __builtin_amdgcn_mfma_f32_16x16x32_bf16(a_rbf, b, c, 0, 0, 0);
    int n = tn*16 + ln;
    int t4 = tn & 3;
    #pragma unroll
    for (int r = 0; r < 4; r++){
      float hi_ = (tn < 4) ? lo_bf(hiw[r][t4]) : hi_bf(hiw[r][t4]);
      float hj_ = (tn < 4) ? lo_bf(hjw[r][t4]) : hi_bf(hjw[r][t4]);
      float mv = c[r] * hi_ * hj_;
      tileF[wv][q*4 + r][n] = mv;
      tileM[wv][q*4 + r][n] = f2b(mv);
    }
  }

  // atom segment flush (fp32 float2 per lane)
  {
    int seg = 0;
    for (int m = 1; m <= 16; m++){
      if (m == 16 || iiS[wv][m] != iiS[wv][seg]){
        int ii = iiS[wv][seg];
        float s0 = 0.f, s1 = 0.f;
        for (int r = seg; r < m; r++){
          float2 w = *(const float2*)&tileF[wv][r][c0];
          s0 += w.x; s1 += w.y;
        }
        atomicAdd(&atom[(size_t)ii*NF + c0],     s0);
        atomicAdd(&atom[(size_t)ii*NF + c0 + 1], s1);
        seg = m;
      }
    }
  }

  // c2 = msg @ w21, c1 = msg @ w11
  floatx4 c2[8];
  #pragma unroll
  for (int tn = 0; tn < 8; tn++) c2[tn] = (floatx4){0,0,0,0};
  #pragma unroll
  for (int tk = 0; tk < 4; tk++){
    short8 a = *(const short8*)&tileM[wv][ln][tk*32 + q*8];
    #pragma unroll
    for (int tn = 0; tn < 8; tn++){
      short8 b = *(const short8*)(w21sw + (size_t)((tk*8 + tn)*64 + lane)*8);
      c2[tn] = __builtin_amdgcn_mfma_f32_16x16x32_bf16(a, b, c2[tn], 0, 0, 0);
    }
  }
  floatx4 c1[8];
  #pragma unroll
  for (int tn = 0; tn < 8; tn++) c1[tn] = (floatx4){0,0,0,0};
  #pragma unroll
  for (int tk = 0; tk < 4; tk++){
    short8 a = *(const short8*)&tileM[wv][ln][tk*32 + q*8];
    #pragma unroll
    for (int tn = 0; tn < 8; tn++){
      short8 b = *(const short8*)(w11sw + (size_t)((tk*8 + tn)*64 + lane)*8);
      c1[tn] = __builtin_amdgcn_mfma_f32_16x16x32_bf16(a, b, c1[tn], 0, 0, 0);
    }
  }
  #pragma unroll
  for (int tn = 0; tn < 8; tn++){
    int n = tn*16 + ln;
    #pragma unroll
    for (int r = 0; r < 4; r++){
      tileM[wv][q*4 + r][n] = f2b(fast_silu(c1[tn][r]));
      c2[tn][r] = fast_silu(c2[tn][r]);
    }
  }

  // g1 = t1 @ w12
  floatx4 g1[8];
  #pragma unroll
  for (int tn = 0; tn < 8; tn++) g1[tn] = (floatx4){0,0,0,0};
  #pragma unroll
  for (int tk = 0; tk < 4; tk++){
    short8 a = *(const short8*)&tileM[wv][ln][tk*32 + q*8];
    #pragma unroll
    for (int tn = 0; tn < 8; tn++){
      short8 b = *(const short8*)(w12sw + (size_t)((tk*8 + tn)*64 + lane)*8);
      g1[tn] = __builtin_amdgcn_mfma_f32_16x16x32_bf16(a, b, g1[tn], 0, 0, 0);
    }
  }
  // t2 -> tileM
  #pragma unroll
  for (int tn = 0; tn < 8; tn++){
    int n = tn*16 + ln;
    #pragma unroll
    for (int r = 0; r < 4; r++) tileM[wv][q*4 + r][n] = f2b(c2[tn][r]);
  }
  // g2 = t2 @ w22 (reuse c1)
  #pragma unroll
  for (int tn = 0; tn < 8; tn++) c1[tn] = (floatx4){0,0,0,0};
  #pragma unroll
  for (int tk = 0; tk < 4; tk++){
    short8 a = *(const short8*)&tileM[wv][ln][tk*32 + q*8];
    #pragma unroll
    for (int tn = 0; tn < 8; tn++){
      short8 b = *(const short8*)(w22sw + (size_t)((tk*8 + tn)*64 + lane)*8);
      c1[tn] = __builtin_amdgcn_mfma_f32_16x16x32_bf16(a, b, c1[tn], 0, 0, 0);
    }
  }

  // three d-passes: tileF <- g1*dir + g2*force_old[j]; fp32 flush -> fdelta
  for (int d = 0; d < 3; d++){
    u32 fjw[4][4];
    #pragma unroll
    for (int r = 0; r < 4; r++)
      #pragma unroll
      for (int t4 = 0; t4 < 4; t4++)
        fjw[r][t4] = forceb[((size_t)jjR[r]*3 + d)*64 + t4*16 + ln];
    #pragma unroll
    for (int tn = 0; tn < 8; tn++){
      int n = tn*16 + ln;
      int t4 = tn & 3;
      #pragma unroll
      for (int r = 0; r < 4; r++){
        float fj = (tn < 4) ? lo_bf(fjw[r][t4]) : hi_bf(fjw[r][t4]);
        tileF[wv][q*4 + r][n] = g1[tn][r]*dirR[r][d] + c1[tn][r]*fj;
      }
    }
    int seg = 0;
    for (int m = 1; m <= 16; m++){
      if (m == 16 || iiS[wv][m] != iiS[wv][seg]){
        int ii = iiS[wv][seg];
        float s0 = 0.f, s1 = 0.f;
        for (int r = seg; r < m; r++){
          float2 w = *(const float2*)&tileF[wv][r][c0];
          s0 += w.x; s1 += w.y;
        }
        atomicAdd(&fdelta[((size_t)ii*3 + d)*NF + c0],     s0);
        atomicAdd(&fdelta[((size_t)ii*3 + d)*NF + c0 + 1], s1);
        seg = m;
      }
    }
  }
}

// ---------------- node phase A: per (tile,d) force update + eu MFMA + product partial ----------------
__global__ __launch_bounds__(64, 4) void k_node_upd(
    float* __restrict__ force, float* __restrict__ fdelta,
    const u16* __restrict__ eusw, u32* __restrict__ forceb,
    float* __restrict__ saccp)
{
  __shared__ __align__(16) u16 tile[16][TPS];
  __shared__ __align__(16) float tileF[16][TPF];
  const int lane = threadIdx.x;
  const int q = lane >> 4, ln = lane & 15;
  const int n0 = blockIdx.x * 16;   // 625 blocks
  const int d  = blockIdx.y;        // 0..2

  #pragma unroll
  for (int m = 0; m < 16; m++){
    size_t idx = ((size_t)(n0+m)*3 + d)*NF + lane;
    float v0 = force[idx]    + fdelta[idx];
    float v1 = force[idx+64] + fdelta[idx+64];
    force[idx] = v0; force[idx+64] = v1;
    fdelta[idx] = 0.f; fdelta[idx+64] = 0.f;
    forceb[((size_t)(n0+m)*3 + d)*64 + lane] = packbf(v0, v1);
    tile[m][lane]    = f2b(v0);
    tile[m][lane+64] = f2b(v1);
    tileF[m][lane]    = v0;
    tileF[m][lane+64] = v1;
  }
  floatx4 c[8];
  #pragma unroll
  for (int tn = 0; tn < 8; tn++) c[tn] = (floatx4){0,0,0,0};
  #pragma unroll
  for (int tk = 0; tk < 4; tk++){
    short8 a = *(const short8*)&tile[ln][tk*32 + q*8];
    #pragma unroll
    for (int tn = 0; tn < 8; tn++){
      short8 b = *(const short8*)(eusw + (size_t)((tk*8 + tn)*64 + lane)*8);
      c[tn] = __builtin_amdgcn_mfma_f32_16x16x32_bf16(a, b, c[tn], 0, 0, 0);
    }
  }
  #pragma unroll
  for (int tn = 0; tn < 8; tn++){
    int n = tn*16 + ln;
    #pragma unroll
    for (int r = 0; r < 4; r++)
      saccp[((size_t)d*NN + n0 + q*4 + r)*NF + n] = tileF[q*4 + r][n] * c[tn][r];
  }
}

// ---------------- node phase B: atom += sum_d partial; then MLP(l+1) ----------------
__global__ __launch_bounds__(64, 2) void k_node_mlpB(
    const float* __restrict__ saccp, float* __restrict__ atom,
    const u16* __restrict__ w1sw, const float* __restrict__ b1,
    const u16* __restrict__ w2sw, const float* __restrict__ b2,
    u32* __restrict__ hb, int do_mlp)
{
  __shared__ __align__(16) u16 tile[16][TPS];
  const int lane = threadIdx.x;
  const int q = lane >> 4, ln = lane & 15;
  const int n0 = blockIdx.x * 16;

  float anew[8][4];
  #pragma unroll
  for (int tn = 0; tn < 8; tn++){
    int n = tn*16 + ln;
    #pragma unroll
    for (int r = 0; r < 4; r++){
      size_t p = ((size_t)(n0 + q*4 + r))*NF + n;
      float s = saccp[p] + saccp[(size_t)NN*NF + p] + saccp[(size_t)2*NN*NF + p];
      size_t idx = (size_t)(n0 + q*4 + r)*NF + n;
      float v = atom[idx] + s;
      atom[idx] = v;
      anew[tn][r] = v;
    }
  }
  if (!do_mlp) return;

  #pragma unroll
  for (int tn = 0; tn < 8; tn++){
    int n = tn*16 + ln;
    #pragma unroll
    for (int r = 0; r < 4; r++) tile[q*4 + r][n] = f2b(anew[tn][r]);
  }
  floatx4 c1[8];
  #pragma unroll
  for (int tn = 0; tn < 8; tn++) c1[tn] = (floatx4){0,0,0,0};
  #pragma unroll
  for (int tk = 0; tk < 4; tk++){
    short8 a = *(const short8*)&tile[ln][tk*32 + q*8];
    #pragma unroll
    for (int tn = 0; tn < 8; tn++){
      short8 b = *(const short8*)(w1sw + (size_t)((tk*8 + tn)*64 + lane)*8);
      c1[tn] = __builtin_amdgcn_mfma_f32_16x16x32_bf16(a, b, c1[tn], 0, 0, 0);
    }
  }
  #pragma unroll
  for (int tn = 0; tn < 8; tn++){
    int n = tn*16 + ln;
    float bias = b1[n];
    #pragma unroll
    for (int r = 0; r < 4; r++)
      tile[q*4 + r][n] = f2b(fast_silu(c1[tn][r] + bias));
  }
  floatx4 c2[8];
  #pragma unroll
  for (int tn = 0; tn < 8; tn++) c2[tn] = (floatx4){0,0,0,0};
  #pragma unroll
  for (int tk = 0; tk < 4; tk++){
    short8 a = *(const short8*)&tile[ln][tk*32 + q*8];
    #pragma unroll
    for (int tn = 0; tn < 8; tn++){
      short8 b = *(const short8*)(w2sw + (size_t)((tk*8 + tn)*64 + lane)*8);
      c2[tn] = __builtin_amdgcn_mfma_f32_16x16x32_bf16(a, b, c2[tn], 0, 0, 0);
    }
  }
  float b2n[8];
  #pragma unroll
  for (int tn = 0; tn < 8; tn++) b2n[tn] = b2[tn*16 + ln];
  #pragma unroll
  for (int tn = 0; tn < 4; tn++){
    #pragma unroll
    for (int r = 0; r < 4; r++){
      float vl = c2[tn][r]   + b2n[tn];
      float vh = c2[tn+4][r] + b2n[tn+4];
      hb[(size_t)(n0 + q*4 + r)*64 + tn*16 + ln] = packbf(vl, vh);
    }
  }
}

// ---------------- write out ----------------
__global__ __launch_bounds__(256) void k_writeout(const float* __restrict__ atom,
                                                  const float* __restrict__ force,
                                                  void* __restrict__ out,
                                                  const int* __restrict__ flag){
  int idx = blockIdx.x * 256 + threadIdx.x;
  const int na = NN * NF;
  const int tot = na + NN * 3 * NF;
  if (idx >= tot) return;
  float v = (idx < na) ? atom[idx] : force[idx - na];
  if (*flag) ((__hip_bfloat16*)out)[idx] = __float2bfloat16(v);
  else       ((float*)out)[idx] = v;
}

extern "C" void kernel_launch(void* const* d_in, const int* in_sizes, int n_in,
                              void* d_out, int out_size, void* d_ws, size_t ws_size,
                              hipStream_t stream){
  const int* z    = (const int*)d_in[0];
  const void* pos = d_in[1];
  // d_in[2] cell, d_in[3] batch: numerically dead (sym == I)
  const int* ei   = (const int*)d_in[4];
  const void* emb   = d_in[5];
  const void* mnpW1 = d_in[6];
  const void* mnpb1 = d_in[7];
  const void* mnpW2 = d_in[8];
  const void* mnpb2 = d_in[9];
  const void* meW   = d_in[10];
  const void* em1W1 = d_in[11];
  const void* em1W2 = d_in[12];
  const void* em2W1 = d_in[13];
  const void* em2W2 = d_in[14];
  const void* euW   = d_in[15];

  float* base  = (float*)d_ws;
  int*   flag  = (int*)d_ws;                  // 4 floats reserved
  float* atom   = base + 4;                   // NN*NF
  float* force  = atom   + NN*NF;             // NN*3*NF
  float* fdelta = force  + (size_t)NN*3*NF;   // NN*3*NF
  u32*   forceb = (u32*)(fdelta + (size_t)NN*3*NF);  // NN*3*64
  int*   count  = (int*)(forceb + (size_t)NN*3*64);  // NN
  // single memset zeroes force, fdelta, forceb, count (contiguous)
  float* ds    = (float*)(count + NN);
  float* dirs  = ds + NE;
  float* posf  = dirs + 3*NE;
  float* embf  = posf + NN*3;
  float* b1f   = embf + 119*NF;               // 3*NF
  float* b2f_  = b1f + 3*NF;                  // 3*NF
  u32*   hb    = (u32*)(b2f_ + 3*NF);         // NN*64
  u16*   mesw  = (u16*)(hb + (size_t)NN*64);  // 3*4096
  u16*   w11sw = mesw  + 3*4096;
  u16*   w12sw = w11sw + 3*16384;
  u16*   w21sw = w12sw + 3*16384;
  u16*   w22sw = w21sw + 3*16384;
  u16*   w1sw  = w22sw + 3*16384;
  u16*   w2sw  = w1sw  + 3*16384;
  u16*   eusw  = w2sw  + 3*16384;
  int* rowptr  = (int*)(eusw + 3*16384);      // NN+1
  int* cursor  = rowptr + NN + 1;
  int* iis     = cursor + NN;                 // NE
  int* jjs     = iis + NE;
  float* saccp = (float*)(jjs + NE);          // 3*NN*NF

  k_detect<<<1, 256, 0, stream>>>(meW, 3*NB*NF, flag);

  // zero force + fdelta + forceb + count in one shot
  hipMemsetAsync(force, 0, ((size_t)NN*3*NF*2 + (size_t)NN*3*64 + NN)*4, stream);

  PrepArgs pa;
  pa.csrc[0]=pos;   pa.cdst[0]=posf; pa.cn[0]=NN*3;
  pa.csrc[1]=emb;   pa.cdst[1]=embf; pa.cn[1]=119*NF;
  pa.csrc[2]=mnpb1; pa.cdst[2]=b1f;  pa.cn[2]=3*NF;
  pa.csrc[3]=mnpb2; pa.cdst[3]=b2f_; pa.cn[3]=3*NF;
  pa.ssrc[0]=em1W1; pa.sdst[0]=w11sw;
  pa.ssrc[1]=em1W2; pa.sdst[1]=w12sw;
  pa.ssrc[2]=em2W1; pa.sdst[2]=w21sw;
  pa.ssrc[3]=em2W2; pa.sdst[3]=w22sw;
  pa.ssrc[4]=mnpW1; pa.sdst[4]=w1sw;
  pa.ssrc[5]=mnpW2; pa.sdst[5]=w2sw;
  pa.ssrc[6]=euW;   pa.sdst[6]=eusw;
  pa.mesrc=meW;     pa.medst=mesw;
  k_prep<<<dim3(192,12), 256, 0, stream>>>(pa, flag);

  k_hist         <<<(NE+255)/256, 256, 0, stream>>>(ei, count);
  k_scan         <<<1, 256, 0, stream>>>(count, rowptr, cursor);
  k_scatter_embed<<<(NE+255)/256, 256, 0, stream>>>(ei, cursor, posf, iis, jjs, ds, dirs);

  k_mlp0<<<NN/16, 64, 0, stream>>>(z, embf, atom, w1sw, b1f, w2sw, b2f_, hb);
  for (int l = 0; l < 3; l++){
    k_edge_mfma<<<NE/32, 128, 0, stream>>>(iis, jjs, ds, dirs, hb,
        mesw  + (size_t)l*4096,
        w11sw + (size_t)l*16384, w12sw + (size_t)l*16384,
        w21sw + (size_t)l*16384, w22sw + (size_t)l*16384,
        atom, forceb, fdelta);
    k_node_upd<<<dim3(NN/16, 3), 64, 0, stream>>>(force, fdelta,
        eusw + (size_t)l*16384, forceb, saccp);
    int nl = l + 1;
    k_node_mlpB<<<NN/16, 64, 0, stream>>>(saccp, atom,
        w1sw + (size_t)(nl%3)*16384, b1f + (size_t)(nl%3)*NF,
        w2sw + (size_t)(nl%3)*16384, b2f_ + (size_t)(nl%3)*NF,
        hb, (l < 2) ? 1 : 0);
  }

  k_writeout<<<(NN*NF + NN*3*NF + 255)/256, 256, 0, stream>>>(atom, force, d_out, flag);
}

// Round 15
// 607.706 us; speedup vs baseline: 1.0162x; 1.0162x over previous
//
#include <hip/hip_runtime.h>
#include <hip/hip_bf16.h>
#include <math.h>

#define NN 10000
#define NE 160000
#define NF 128
#define NB 20
#define CUT 5.0f
#define TPS 136   // u16 tile row stride
#define TPF 132   // fp32 tile row stride

typedef __attribute__((ext_vector_type(8))) short short8;
typedef __attribute__((ext_vector_type(4))) float floatx4;
typedef unsigned short u16;
typedef unsigned int u32;

__device__ __forceinline__ u16 f2b(float x){
  union { __hip_bfloat16 b; u16 u; } cv;
  cv.b = __float2bfloat16(x);
  return cv.u;
}
__device__ __forceinline__ float lo_bf(u32 w){ return __uint_as_float(w << 16); }
__device__ __forceinline__ float hi_bf(u32 w){ return __uint_as_float(w & 0xFFFF0000u); }
__device__ __forceinline__ u32 packbf(float lo, float hi){
  return ((u32)f2b(hi) << 16) | (u32)f2b(lo);
}
__device__ __forceinline__ float fast_silu(float v){
  return v * __builtin_amdgcn_rcpf(1.f + __expf(-v));
}
__device__ __forceinline__ float rdf(const void* p, size_t i, int isb){
  return isb ? __bfloat162float(((const __hip_bfloat16*)p)[i]) : ((const float*)p)[i];
}

// ---------------- dtype detector: 1=bf16, 0=fp32 ----------------
__global__ __launch_bounds__(256) void k_detect(const void* __restrict__ w, int nelem,
                                                int* __restrict__ flag){
  __shared__ int cnt;
  if (threadIdx.x == 0) cnt = 0;
  __syncthreads();
  const u16* hw = (const u16*)w;
  int local = 0;
  for (int k = threadIdx.x; k < nelem; k += 256){
    u16 h = hw[k];
    int e = (h >> 7) & 0xFF;
    if ((h & 0x7FFF) == 0 || (e >= 103 && e <= 130)) local++;
  }
  atomicAdd(&cnt, local);
  __syncthreads();
  if (threadIdx.x == 0) *flag = (cnt >= (nelem * 9) / 10) ? 1 : 0;
}

// ---------------- single prep kernel ----------------
struct PrepArgs {
  const void* csrc[4]; float* cdst[4]; int cn[4];
  const void* ssrc[7]; u16* sdst[7];
  const void* mesrc;   u16* medst;
};
__global__ __launch_bounds__(256) void k_prep(PrepArgs a, const int* __restrict__ flag){
  int y = blockIdx.y;
  int isb = *flag;
  if (y < 4){
    const void* s = a.csrc[y]; float* d = a.cdst[y]; int n = a.cn[y];
    for (int i = blockIdx.x*256 + threadIdx.x; i < n; i += gridDim.x*256)
      d[i] = rdf(s, i, isb);
  } else if (y < 11){
    const void* s = a.ssrc[y-4]; u16* d = a.sdst[y-4];
    int idx = blockIdx.x*256 + threadIdx.x;
    int l = idx >> 14, rem = idx & 16383;
    int j = rem & 7, lane = (rem >> 3) & 63, tn = (rem >> 9) & 7, tk = rem >> 12;
    int k = tk*32 + ((lane >> 4) & 3)*8 + j, n = tn*16 + (lane & 15);
    d[idx] = f2b(rdf(s, (size_t)l*16384 + k*NF + n, isb));
  } else {
    int idx = blockIdx.x*256 + threadIdx.x;
    if (idx >= 3*4096) return;
    int l = idx >> 12, rem = idx & 4095;
    int j = rem & 7, lane = (rem >> 3) & 63, tn = rem >> 9;
    int k = ((lane >> 4) & 3)*8 + j, n = tn*16 + (lane & 15);
    a.medst[idx] = (k < NB) ? f2b(rdf(a.mesrc, (size_t)l*NB*NF + k*NF + n, isb)) : (u16)0;
  }
}

// ---------------- counting sort: hist -> scan -> fused scatter+embed ----------------
__global__ __launch_bounds__(256) void k_hist(const int* __restrict__ ei, int* __restrict__ count){
  int e = blockIdx.x*256 + threadIdx.x;
  if (e < NE) atomicAdd(&count[ei[e]], 1);
}
__global__ __launch_bounds__(256) void k_scan(const int* __restrict__ count,
                                              int* __restrict__ rowptr, int* __restrict__ cursor){
  __shared__ int part[256];
  const int CH = (NN + 255) / 256;
  int t = threadIdx.x;
  int base = t * CH;
  int s = 0;
  for (int k = 0; k < CH; k++){ int i = base + k; if (i < NN) s += count[i]; }
  part[t] = s;
  __syncthreads();
  for (int off = 1; off < 256; off <<= 1){
    int v = (t >= off) ? part[t - off] : 0;
    __syncthreads();
    part[t] += v;
    __syncthreads();
  }
  int run = (t == 0) ? 0 : part[t - 1];
  for (int k = 0; k < CH; k++){
    int i = base + k;
    if (i < NN){ rowptr[i] = run; cursor[i] = run; run += count[i]; }
  }
  if (t == 255) rowptr[NN] = run;
}
__global__ __launch_bounds__(256) void k_scatter_embed(const int* __restrict__ ei,
                                                       int* __restrict__ cursor,
                                                       const float* __restrict__ pos,
                                                       int* __restrict__ iis, int* __restrict__ jjs,
                                                       float* __restrict__ ds, float* __restrict__ dirs){
  int e = blockIdx.x * 256 + threadIdx.x;
  if (e >= NE) return;
  int i = ei[e], j = ei[NE + e];
  float dx = pos[j*3+0] - pos[i*3+0];
  float dy = pos[j*3+1] - pos[i*3+1];
  float dz = pos[j*3+2] - pos[i*3+2];
  float d = sqrtf(dx*dx + dy*dy + dz*dz + 1e-12f);
  float inv = 1.0f / d;
  int s = atomicAdd(&cursor[i], 1);
  iis[s] = i; jjs[s] = j;
  ds[s] = d;
  dirs[s*3+0] = dx*inv; dirs[s*3+1] = dy*inv; dirs[s*3+2] = dz*inv;
}

// ---------------- layer-0 node MLP with fused atom init ----------------
__global__ __launch_bounds__(64, 4) void k_mlp0(
    const int* __restrict__ z, const float* __restrict__ emb,
    float* __restrict__ atom,
    const u16* __restrict__ w1sw, const float* __restrict__ b1,
    const u16* __restrict__ w2sw, const float* __restrict__ b2,
    u32* __restrict__ hb)
{
  __shared__ __align__(16) u16 tileT[16][TPS];
  const int lane = threadIdx.x;
  const int q = lane >> 4, ln = lane & 15;
  const int n0 = blockIdx.x * 16;
  const int zn = z[n0 + ln];

  floatx4 c1[8];
  #pragma unroll
  for (int tn = 0; tn < 8; tn++) c1[tn] = (floatx4){0,0,0,0};
  #pragma unroll
  for (int tk = 0; tk < 4; tk++){
    const float4 u0 = *(const float4*)&emb[(size_t)zn*NF + tk*32 + q*8];
    const float4 u1 = *(const float4*)&emb[(size_t)zn*NF + tk*32 + q*8 + 4];
    *(float4*)&atom[(size_t)(n0+ln)*NF + tk*32 + q*8]     = u0;
    *(float4*)&atom[(size_t)(n0+ln)*NF + tk*32 + q*8 + 4] = u1;
    short8 a;
    a[0]=(short)f2b(u0.x); a[1]=(short)f2b(u0.y); a[2]=(short)f2b(u0.z); a[3]=(short)f2b(u0.w);
    a[4]=(short)f2b(u1.x); a[5]=(short)f2b(u1.y); a[6]=(short)f2b(u1.z); a[7]=(short)f2b(u1.w);
    #pragma unroll
    for (int tn = 0; tn < 8; tn++){
      short8 b = *(const short8*)(w1sw + (size_t)((tk*8 + tn)*64 + lane)*8);
      c1[tn] = __builtin_amdgcn_mfma_f32_16x16x32_bf16(a, b, c1[tn], 0, 0, 0);
    }
  }
  #pragma unroll
  for (int tn = 0; tn < 8; tn++){
    int n = tn*16 + ln;
    float bias = b1[n];
    #pragma unroll
    for (int r = 0; r < 4; r++)
      tileT[q*4 + r][n] = f2b(fast_silu(c1[tn][r] + bias));
  }
  floatx4 c2[8];
  #pragma unroll
  for (int tn = 0; tn < 8; tn++) c2[tn] = (floatx4){0,0,0,0};
  #pragma unroll
  for (int tk = 0; tk < 4; tk++){
    short8 a = *(const short8*)&tileT[ln][tk*32 + q*8];
    #pragma unroll
    for (int tn = 0; tn < 8; tn++){
      short8 b = *(const short8*)(w2sw + (size_t)((tk*8 + tn)*64 + lane)*8);
      c2[tn] = __builtin_amdgcn_mfma_f32_16x16x32_bf16(a, b, c2[tn], 0, 0, 0);
    }
  }
  float b2n[8];
  #pragma unroll
  for (int tn = 0; tn < 8; tn++) b2n[tn] = b2[tn*16 + ln];
  #pragma unroll
  for (int tn = 0; tn < 4; tn++){
    #pragma unroll
    for (int r = 0; r < 4; r++){
      float vl = c2[tn][r]   + b2n[tn];
      float vh = c2[tn+4][r] + b2n[tn+4];
      hb[(size_t)(n0 + q*4 + r)*64 + tn*16 + ln] = packbf(vl, vh);
    }
  }
}

// ---------------- MFMA edge kernel: XCD-swizzled blocks, merged c1/c2 A-reads ----------------
__global__ __launch_bounds__(128, 2) void k_edge_mfma(
    const int* __restrict__ iis, const int* __restrict__ jjs,
    const float* __restrict__ ds, const float* __restrict__ dirs,
    const u32* __restrict__ hb,
    const u16* __restrict__ mesw,
    const u16* __restrict__ w11sw, const u16* __restrict__ w12sw,
    const u16* __restrict__ w21sw, const u16* __restrict__ w22sw,
    float* __restrict__ atom, const u32* __restrict__ forceb, float* __restrict__ fdelta)
{
  __shared__ __align__(16) u16 tileM[2][16][TPS];
  __shared__ __align__(16) float tileF[2][16][TPF];
  __shared__ int iiS[2][16];

  const int wv = threadIdx.x >> 6;
  const int lane = threadIdx.x & 63;
  const int q = lane >> 4, ln = lane & 15;
  // XCD-aware swizzle: assuming XCD = blockIdx % 8, give each XCD a contiguous
  // chunk of the destination-sorted edge list so its atom/fdelta slices and hot
  // hb/forceb rows stay in its 4 MB L2. Pure perf heuristic — any permutation is correct.
  const int bid = (blockIdx.x & 7) * (gridDim.x >> 3) + (blockIdx.x >> 3);  // grid 5000 % 8 == 0
  const int e0 = (bid*2 + wv) * 16;
  const int c0 = lane * 2;

  if (lane < 16) iiS[wv][lane] = iis[e0 + lane];

  int iiR[4], jjR[4];
  float dirR[4][3];
  #pragma unroll
  for (int r = 0; r < 4; r++){
    int s = e0 + q*4 + r;
    iiR[r] = iis[s]; jjR[r] = jjs[s];
    dirR[r][0] = dirs[s*3+0]; dirR[r][1] = dirs[s*3+1]; dirR[r][2] = dirs[s*3+2];
  }

  u32 hiw[4][4], hjw[4][4];
  #pragma unroll
  for (int r = 0; r < 4; r++)
    #pragma unroll
    for (int t4 = 0; t4 < 4; t4++){
      hiw[r][t4] = hb[(size_t)iiR[r]*64 + t4*16 + ln];
      hjw[r][t4] = hb[(size_t)jjR[r]*64 + t4*16 + ln];
    }

  float dA  = ds[e0 + ln];
  float fcA = (dA < CUT) ? 0.5f*(cosf((float)M_PI*dA*(1.0f/CUT)) + 1.0f) : 0.0f;
  short8 a_rbf;
  #pragma unroll
  for (int j = 0; j < 8; j++){
    int k = q*8 + j;
    float v = 0.f;
    if (k < NB){
      float t = (dA - CUT*(float)k/(float)(NB-1)) * ((float)NB/CUT);
      v = __expf(-t*t) * fcA;
    }
    a_rbf[j] = (short)f2b(v);
  }

  // me = rbf @ meW; msg -> tileF (fp32 flush) + tileM (bf16 MFMA)
  #pragma unroll
  for (int tn = 0; tn < 8; tn++){
    short8 b = *(const short8*)(mesw + (size_t)(tn*64 + lane)*8);
    floatx4 c = {0.f,0.f,0.f,0.f};
    c = __builtin_amdgcn_mfma_f32_16x16x32_bf16(a_rbf, b, c, 0, 0, 0);
    int n = tn*16 + ln;
    int t4 = tn & 3;
    #pragma unroll
    for (int r = 0; r < 4; r++){
      float hi_ = (tn < 4) ? lo_bf(hiw[r][t4]) : hi_bf(hiw[r][t4]);
      float hj_ = (tn < 4) ? lo_bf(hjw[r][t4]) : hi_bf(hjw[r][t4]);
      float mv = c[r] * hi_ * hj_;
      tileF[wv][q*4 + r][n] = mv;
      tileM[wv][q*4 + r][n] = f2b(mv);
    }
  }

  // atom segment flush (fp32 float2 per lane)
  {
    int seg = 0;
    for (int m = 1; m <= 16; m++){
      if (m == 16 || iiS[wv][m] != iiS[wv][seg]){
        int ii = iiS[wv][seg];
        float s0 = 0.f, s1 = 0.f;
        for (int r = seg; r < m; r++){
          float2 w = *(const float2*)&tileF[wv][r][c0];
          s0 += w.x; s1 += w.y;
        }
        atomicAdd(&atom[(size_t)ii*NF + c0],     s0);
        atomicAdd(&atom[(size_t)ii*NF + c0 + 1], s1);
        seg = m;
      }
    }
  }

  // merged pass: one A-read feeds both c2 = msg @ w21 and c1 = msg @ w11
  floatx4 c2[8], c1[8];
  #pragma unroll
  for (int tn = 0; tn < 8; tn++){ c2[tn] = (floatx4){0,0,0,0}; c1[tn] = (floatx4){0,0,0,0}; }
  #pragma unroll
  for (int tk = 0; tk < 4; tk++){
    short8 a = *(const short8*)&tileM[wv][ln][tk*32 + q*8];
    #pragma unroll
    for (int tn = 0; tn < 8; tn++){
      short8 b2 = *(const short8*)(w21sw + (size_t)((tk*8 + tn)*64 + lane)*8);
      c2[tn] = __builtin_amdgcn_mfma_f32_16x16x32_bf16(a, b2, c2[tn], 0, 0, 0);
      short8 b1 = *(const short8*)(w11sw + (size_t)((tk*8 + tn)*64 + lane)*8);
      c1[tn] = __builtin_amdgcn_mfma_f32_16x16x32_bf16(a, b1, c1[tn], 0, 0, 0);
    }
  }
  #pragma unroll
  for (int tn = 0; tn < 8; tn++){
    int n = tn*16 + ln;
    #pragma unroll
    for (int r = 0; r < 4; r++){
      tileM[wv][q*4 + r][n] = f2b(fast_silu(c1[tn][r]));
      c2[tn][r] = fast_silu(c2[tn][r]);
    }
  }

  // g1 = t1 @ w12
  floatx4 g1[8];
  #pragma unroll
  for (int tn = 0; tn < 8; tn++) g1[tn] = (floatx4){0,0,0,0};
  #pragma unroll
  for (int tk = 0; tk < 4; tk++){
    short8 a = *(const short8*)&tileM[wv][ln][tk*32 + q*8];
    #pragma unroll
    for (int tn = 0; tn < 8; tn++){
      short8 b = *(const short8*)(w12sw + (size_t)((tk*8 + tn)*64 + lane)*8);
      g1[tn] = __builtin_amdgcn_mfma_f32_16x16x32_bf16(a, b, g1[tn], 0, 0, 0);
    }
  }
  // t2 -> tileM
  #pragma unroll
  for (int tn = 0; tn < 8; tn++){
    int n = tn*16 + ln;
    #pragma unroll
    for (int r = 0; r < 4; r++) tileM[wv][q*4 + r][n] = f2b(c2[tn][r]);
  }
  // g2 = t2 @ w22 (reuse c1)
  #pragma unroll
  for (int tn = 0; tn < 8; tn++) c1[tn] = (floatx4){0,0,0,0};
  #pragma unroll
  for (int tk = 0; tk < 4; tk++){
    short8 a = *(const short8*)&tileM[wv][ln][tk*32 + q*8];
    #pragma unroll
    for (int tn = 0; tn < 8; tn++){
      short8 b = *(const short8*)(w22sw + (size_t)((tk*8 + tn)*64 + lane)*8);
      c1[tn] = __builtin_amdgcn_mfma_f32_16x16x32_bf16(a, b, c1[tn], 0, 0, 0);
    }
  }

  // three d-passes: tileF <- g1*dir + g2*force_old[j]; fp32 flush -> fdelta
  for (int d = 0; d < 3; d++){
    u32 fjw[4][4];
    #pragma unroll
    for (int r = 0; r < 4; r++)
      #pragma unroll
      for (int t4 = 0; t4 < 4; t4++)
        fjw[r][t4] = forceb[((size_t)jjR[r]*3 + d)*64 + t4*16 + ln];
    #pragma unroll
    for (int tn = 0; tn < 8; tn++){
      int n = tn*16 + ln;
      int t4 = tn & 3;
      #pragma unroll
      for (int r = 0; r < 4; r++){
        float fj = (tn < 4) ? lo_bf(fjw[r][t4]) : hi_bf(fjw[r][t4]);
        tileF[wv][q*4 + r][n] = g1[tn][r]*dirR[r][d] + c1[tn][r]*fj;
      }
    }
    int seg = 0;
    for (int m = 1; m <= 16; m++){
      if (m == 16 || iiS[wv][m] != iiS[wv][seg]){
        int ii = iiS[wv][seg];
        float s0 = 0.f, s1 = 0.f;
        for (int r = seg; r < m; r++){
          float2 w = *(const float2*)&tileF[wv][r][c0];
          s0 += w.x; s1 += w.y;
        }
        atomicAdd(&fdelta[((size_t)ii*3 + d)*NF + c0],     s0);
        atomicAdd(&fdelta[((size_t)ii*3 + d)*NF + c0 + 1], s1);
        seg = m;
      }
    }
  }
}

// ---------------- node phase A: per (tile,d) force update + eu MFMA + product partial ----------------
__global__ __launch_bounds__(64, 4) void k_node_upd(
    float* __restrict__ force, float* __restrict__ fdelta,
    const u16* __restrict__ eusw, u32* __restrict__ forceb,
    float* __restrict__ saccp)
{
  __shared__ __align__(16) u16 tile[16][TPS];
  __shared__ __align__(16) float tileF[16][TPF];
  const int lane = threadIdx.x;
  const int q = lane >> 4, ln = lane & 15;
  const int n0 = blockIdx.x * 16;
  const int d  = blockIdx.y;

  #pragma unroll
  for (int m = 0; m < 16; m++){
    size_t idx = ((size_t)(n0+m)*3 + d)*NF + lane;
    float v0 = force[idx]    + fdelta[idx];
    float v1 = force[idx+64] + fdelta[idx+64];
    force[idx] = v0; force[idx+64] = v1;
    fdelta[idx] = 0.f; fdelta[idx+64] = 0.f;
    forceb[((size_t)(n0+m)*3 + d)*64 + lane] = packbf(v0, v1);
    tile[m][lane]    = f2b(v0);
    tile[m][lane+64] = f2b(v1);
    tileF[m][lane]    = v0;
    tileF[m][lane+64] = v1;
  }
  floatx4 c[8];
  #pragma unroll
  for (int tn = 0; tn < 8; tn++) c[tn] = (floatx4){0,0,0,0};
  #pragma unroll
  for (int tk = 0; tk < 4; tk++){
    short8 a = *(const short8*)&tile[ln][tk*32 + q*8];
    #pragma unroll
    for (int tn = 0; tn < 8; tn++){
      short8 b = *(const short8*)(eusw + (size_t)((tk*8 + tn)*64 + lane)*8);
      c[tn] = __builtin_amdgcn_mfma_f32_16x16x32_bf16(a, b, c[tn], 0, 0, 0);
    }
  }
  #pragma unroll
  for (int tn = 0; tn < 8; tn++){
    int n = tn*16 + ln;
    #pragma unroll
    for (int r = 0; r < 4; r++)
      saccp[((size_t)d*NN + n0 + q*4 + r)*NF + n] = tileF[q*4 + r][n] * c[tn][r];
  }
}

// ---------------- node phase B: atom += sum_d partial; then MLP(l+1) ----------------
__global__ __launch_bounds__(64, 2) void k_node_mlpB(
    const float* __restrict__ saccp, float* __restrict__ atom,
    const u16* __restrict__ w1sw, const float* __restrict__ b1,
    const u16* __restrict__ w2sw, const float* __restrict__ b2,
    u32* __restrict__ hb, int do_mlp)
{
  __shared__ __align__(16) u16 tile[16][TPS];
  const int lane = threadIdx.x;
  const int q = lane >> 4, ln = lane & 15;
  const int n0 = blockIdx.x * 16;

  float anew[8][4];
  #pragma unroll
  for (int tn = 0; tn < 8; tn++){
    int n = tn*16 + ln;
    #pragma unroll
    for (int r = 0; r < 4; r++){
      size_t p = ((size_t)(n0 + q*4 + r))*NF + n;
      float s = saccp[p] + saccp[(size_t)NN*NF + p] + saccp[(size_t)2*NN*NF + p];
      size_t idx = (size_t)(n0 + q*4 + r)*NF + n;
      float v = atom[idx] + s;
      atom[idx] = v;
      anew[tn][r] = v;
    }
  }
  if (!do_mlp) return;

  #pragma unroll
  for (int tn = 0; tn < 8; tn++){
    int n = tn*16 + ln;
    #pragma unroll
    for (int r = 0; r < 4; r++) tile[q*4 + r][n] = f2b(anew[tn][r]);
  }
  floatx4 c1[8];
  #pragma unroll
  for (int tn = 0; tn < 8; tn++) c1[tn] = (floatx4){0,0,0,0};
  #pragma unroll
  for (int tk = 0; tk < 4; tk++){
    short8 a = *(const short8*)&tile[ln][tk*32 + q*8];
    #pragma unroll
    for (int tn = 0; tn < 8; tn++){
      short8 b = *(const short8*)(w1sw + (size_t)((tk*8 + tn)*64 + lane)*8);
      c1[tn] = __builtin_amdgcn_mfma_f32_16x16x32_bf16(a, b, c1[tn], 0, 0, 0);
    }
  }
  #pragma unroll
  for (int tn = 0; tn < 8; tn++){
    int n = tn*16 + ln;
    float bias = b1[n];
    #pragma unroll
    for (int r = 0; r < 4; r++)
      tile[q*4 + r][n] = f2b(fast_silu(c1[tn][r] + bias));
  }
  floatx4 c2[8];
  #pragma unroll
  for (int tn = 0; tn < 8; tn++) c2[tn] = (floatx4){0,0,0,0};
  #pragma unroll
  for (int tk = 0; tk < 4; tk++){
    short8 a = *(const short8*)&tile[ln][tk*32 + q*8];
    #pragma unroll
    for (int tn = 0; tn < 8; tn++){
      short8 b = *(const short8*)(w2sw + (size_t)((tk*8 + tn)*64 + lane)*8);
      c2[tn] = __builtin_amdgcn_mfma_f32_16x16x32_bf16(a, b, c2[tn], 0, 0, 0);
    }
  }
  float b2n[8];
  #pragma unroll
  for (int tn = 0; tn < 8; tn++) b2n[tn] = b2[tn*16 + ln];
  #pragma unroll
  for (int tn = 0; tn < 4; tn++){
    #pragma unroll
    for (int r = 0; r < 4; r++){
      float vl = c2[tn][r]   + b2n[tn];
      float vh = c2[tn+4][r] + b2n[tn+4];
      hb[(size_t)(n0 + q*4 + r)*64 + tn*16 + ln] = packbf(vl, vh);
    }
  }
}

// ---------------- write out ----------------
__global__ __launch_bounds__(256) void k_writeout(const float* __restrict__ atom,
                                                  const float* __restrict__ force,
                                                  void* __restrict__ out,
                                                  const int* __restrict__ flag){
  int idx = blockIdx.x * 256 + threadIdx.x;
  const int na = NN * NF;
  const int tot = na + NN * 3 * NF;
  if (idx >= tot) return;
  float v = (idx < na) ? atom[idx] : force[idx - na];
  if (*flag) ((__hip_bfloat16*)out)[idx] = __float2bfloat16(v);
  else       ((float*)out)[idx] = v;
}

extern "C" void kernel_launch(void* const* d_in, const int* in_sizes, int n_in,
                              void* d_out, int out_size, void* d_ws, size_t ws_size,
                              hipStream_t stream){
  const int* z    = (const int*)d_in[0];
  const void* pos = d_in[1];
  // d_in[2] cell, d_in[3] batch: numerically dead (sym == I)
  const int* ei   = (const int*)d_in[4];
  const void* emb   = d_in[5];
  const void* mnpW1 = d_in[6];
  const void* mnpb1 = d_in[7];
  const void* mnpW2 = d_in[8];
  const void* mnpb2 = d_in[9];
  const void* meW   = d_in[10];
  const void* em1W1 = d_in[11];
  const void* em1W2 = d_in[12];
  const void* em2W1 = d_in[13];
  const void* em2W2 = d_in[14];
  const void* euW   = d_in[15];

  float* base  = (float*)d_ws;
  int*   flag  = (int*)d_ws;                  // 4 floats reserved
  float* atom   = base + 4;                   // NN*NF
  float* force  = atom   + NN*NF;             // NN*3*NF
  float* fdelta = force  + (size_t)NN*3*NF;   // NN*3*NF
  u32*   forceb = (u32*)(fdelta + (size_t)NN*3*NF);  // NN*3*64
  int*   count  = (int*)(forceb + (size_t)NN*3*64);  // NN
  float* ds    = (float*)(count + NN);
  float* dirs  = ds + NE;
  float* posf  = dirs + 3*NE;
  float* embf  = posf + NN*3;
  float* b1f   = embf + 119*NF;
  float* b2f_  = b1f + 3*NF;
  u32*   hb    = (u32*)(b2f_ + 3*NF);
  u16*   mesw  = (u16*)(hb + (size_t)NN*64);
  u16*   w11sw = mesw  + 3*4096;
  u16*   w12sw = w11sw + 3*16384;
  u16*   w21sw = w12sw + 3*16384;
  u16*   w22sw = w21sw + 3*16384;
  u16*   w1sw  = w22sw + 3*16384;
  u16*   w2sw  = w1sw  + 3*16384;
  u16*   eusw  = w2sw  + 3*16384;
  int* rowptr  = (int*)(eusw + 3*16384);
  int* cursor  = rowptr + NN + 1;
  int* iis     = cursor + NN;
  int* jjs     = iis + NE;
  float* saccp = (float*)(jjs + NE);

  k_detect<<<1, 256, 0, stream>>>(meW, 3*NB*NF, flag);

  hipMemsetAsync(force, 0, ((size_t)NN*3*NF*2 + (size_t)NN*3*64 + NN)*4, stream);

  PrepArgs pa;
  pa.csrc[0]=pos;   pa.cdst[0]=posf; pa.cn[0]=NN*3;
  pa.csrc[1]=emb;   pa.cdst[1]=embf; pa.cn[1]=119*NF;
  pa.csrc[2]=mnpb1; pa.cdst[2]=b1f;  pa.cn[2]=3*NF;
  pa.csrc[3]=mnpb2; pa.cdst[3]=b2f_; pa.cn[3]=3*NF;
  pa.ssrc[0]=em1W1; pa.sdst[0]=w11sw;
  pa.ssrc[1]=em1W2; pa.sdst[1]=w12sw;
  pa.ssrc[2]=em2W1; pa.sdst[2]=w21sw;
  pa.ssrc[3]=em2W2; pa.sdst[3]=w22sw;
  pa.ssrc[4]=mnpW1; pa.sdst[4]=w1sw;
  pa.ssrc[5]=mnpW2; pa.sdst[5]=w2sw;
  pa.ssrc[6]=euW;   pa.sdst[6]=eusw;
  pa.mesrc=meW;     pa.medst=mesw;
  k_prep<<<dim3(192,12), 256, 0, stream>>>(pa, flag);

  k_hist         <<<(NE+255)/256, 256, 0, stream>>>(ei, count);
  k_scan         <<<1, 256, 0, stream>>>(count, rowptr, cursor);
  k_scatter_embed<<<(NE+255)/256, 256, 0, stream>>>(ei, cursor, posf, iis, jjs, ds, dirs);

  k_mlp0<<<NN/16, 64, 0, stream>>>(z, embf, atom, w1sw, b1f, w2sw, b2f_, hb);
  for (int l = 0; l < 3; l++){
    k_edge_mfma<<<NE/32, 128, 0, stream>>>(iis, jjs, ds, dirs, hb,
        mesw  + (size_t)l*4096,
        w11sw + (size_t)l*16384, w12sw + (size_t)l*16384,
        w21sw + (size_t)l*16384, w22sw + (size_t)l*16384,
        atom, forceb, fdelta);
    k_node_upd<<<dim3(NN/16, 3), 64, 0, stream>>>(force, fdelta,
        eusw + (size_t)l*16384, forceb, saccp);
    int nl = l + 1;
    k_node_mlpB<<<NN/16, 64, 0, stream>>>(saccp, atom,
        w1sw + (size_t)(nl%3)*16384, b1f + (size_t)(nl%3)*NF,
        w2sw + (size_t)(nl%3)*16384, b2f_ + (size_t)(nl%3)*NF,
        hb, (l < 2) ? 1 : 0);
  }

  k_writeout<<<(NN*NF + NN*3*NF + 255)/256, 256, 0, stream>>>(atom, force, d_out, flag);
}